// Round 6
// baseline (344.831 us; speedup 1.0000x reference)
//
#include <hip/hip_runtime.h>
#include <hip/hip_bf16.h>

// ---------------------------------------------------------------------------
// REMSA fused block on MI355X.
// Shapes: B=4, N=4096, C=1024, H=16, D=64. M = B*N = 16384.
//
// Decomposition:
//   xb   = bf16(x)                                  [M,1024]
//   qkv  = xb @ qkv_w + qkv_b                       [M,3072]   (GEMM, bf16 out)
//   attn = per-token 16x16 head-attention(qkv)      [M,1024]   -> xcat[:, :1024]
//   W2   = conv_w @ pw_w^T (prefused), b2 fused     [1024,1024]
//   xc2  = xb @ W2 + b2                             [M,1024]   (GEMM, bf16 out)
//   xc3  = depthwise3(xc2) + dw_b                   [M,1024]   -> xcat[:, 1024:]
//   out  = xcat @ [out_w; tok_w] + (out_b+tok_b)    [M,1024]   (GEMM K=2048, f32)
//
// gemmMain: 256x128 tile, BK=32, 4 waves (2x2), 3 LDS buffers x 24 KiB =
// 72 KiB -> 2 blocks/CU (role-split: one block's MFMA hides the other's
// read/barrier window). Depth-2 prefetch via global_load_lds, counted
// s_waitcnt vmcnt(6) once per K-tile (never 0 in the loop). 2 phases per
// K-tile of {ds_read + stage-issue + barrier + lgkm(0) + 16 MFMA + barrier}.
// Bank swizzle: 16B chunk kc ^= (row>>1)&3 on the global source (LDS dest
// linear, rule 21) and on ds_read offsets -> 0 conflicts (verified round 4).
// ---------------------------------------------------------------------------

typedef __attribute__((ext_vector_type(8))) short sh8;
typedef __attribute__((ext_vector_type(4))) float f4;

__device__ __forceinline__ float bf2f(short s) {
  unsigned u = ((unsigned)(unsigned short)s) << 16;
  return __builtin_bit_cast(float, u);
}
__device__ __forceinline__ short f2bf(float f) {
  return __builtin_bit_cast(short, __float2bfloat16(f));
}
__device__ __forceinline__ void g2l16(const void* g, void* l) {
  __builtin_amdgcn_global_load_lds(
      (const __attribute__((address_space(1))) unsigned int*)g,
      (__attribute__((address_space(3))) unsigned int*)l, 16, 0, 0);
}

// --------------------------- f32 -> bf16 convert ---------------------------
__global__ __launch_bounds__(256) void cvt_f32_bf16(
    const float* __restrict__ src, short* __restrict__ dst, int n8) {
  int i = blockIdx.x * 256 + threadIdx.x;
  if (i >= n8) return;
  float4 a = ((const float4*)src)[i * 2];
  float4 b = ((const float4*)src)[i * 2 + 1];
  sh8 o;
  o[0] = f2bf(a.x); o[1] = f2bf(a.y); o[2] = f2bf(a.z); o[3] = f2bf(a.w);
  o[4] = f2bf(b.x); o[5] = f2bf(b.y); o[6] = f2bf(b.z); o[7] = f2bf(b.w);
  ((sh8*)dst)[i] = o;
}

// ------------------- transpose f32 (KxN) -> bf16 (N x ldd) -----------------
__global__ __launch_bounds__(256) void transpose_f32_bf16(
    const float* __restrict__ src, short* __restrict__ dst,
    int N, int ldd, int coff) {
  __shared__ float tile[32][33];
  int kb = blockIdx.y * 32, nb = blockIdx.x * 32;
  int tx = threadIdx.x, ty = threadIdx.y;
#pragma unroll
  for (int j = 0; j < 32; j += 8)
    tile[ty + j][tx] = src[(size_t)(kb + ty + j) * N + nb + tx];
  __syncthreads();
#pragma unroll
  for (int j = 0; j < 32; j += 8)
    dst[(size_t)(nb + ty + j) * ldd + coff + kb + tx] = f2bf(tile[tx][ty + j]);
}

// --------------------------- misc bias / dw prep ---------------------------
__global__ __launch_bounds__(256) void prep_misc(
    const float* __restrict__ pw_w, const float* __restrict__ conv_b,
    const float* __restrict__ pw_b, const float* __restrict__ out_b,
    const float* __restrict__ tok_b, const float* __restrict__ dw_w,
    const float* __restrict__ dw_b,
    float* __restrict__ b2, float* __restrict__ bcat,
    float* __restrict__ dw0, float* __restrict__ dw1,
    float* __restrict__ dw2, float* __restrict__ dwb) {
  int o = blockIdx.x;
  float part = 0.f;
  for (int i = threadIdx.x; i < 1024; i += 256)
    part += pw_w[(size_t)o * 1024 + i] * conv_b[i];
#pragma unroll
  for (int off = 32; off >= 1; off >>= 1) part += __shfl_down(part, off);
  __shared__ float red[4];
  int wid = threadIdx.x >> 6, lane = threadIdx.x & 63;
  if (lane == 0) red[wid] = part;
  __syncthreads();
  if (threadIdx.x == 0) {
    float s = red[0] + red[1] + red[2] + red[3];
    b2[o] = s + pw_b[o];
    bcat[o] = out_b[o] + tok_b[o];
    dw0[o] = dw_w[o * 3 + 0];
    dw1[o] = dw_w[o * 3 + 1];
    dw2[o] = dw_w[o * 3 + 2];
    dwb[o] = dw_b[o];
  }
}

// --------------------- bf16 GEMM, 128x128 (prep only) ----------------------
template <int OUT_BF16>
__global__ __launch_bounds__(256, 2) void gemm128(
    const short* __restrict__ A, const short* __restrict__ Bt,
    void* __restrict__ Cp, const float* __restrict__ bias, int K, int ldc) {
  __shared__ short As[128 * 32];
  __shared__ short Bs[128 * 32];
  const int wid = threadIdx.x >> 6, lane = threadIdx.x & 63;
  const int bm = blockIdx.y, bn = blockIdx.x;
  const int wr = wid >> 1, wc = wid & 1;
  const size_t abase = (size_t)bm * 128 * K;
  const size_t bbase = (size_t)bn * 128 * K;
  const int r16 = lane & 15, ko = (lane >> 4) * 8;

  f4 acc[4][4] = {};

  for (int k0 = 0; k0 < K; k0 += 32) {
    __syncthreads();
#pragma unroll
    for (int c = 0; c < 2; ++c) {
      int ch = c * 256 + wid * 64 + lane;
      int row = ch >> 2, kc = (ch & 3) * 8;
      g2l16(A + abase + (size_t)row * K + k0 + kc, &As[ch * 8]);
      g2l16(Bt + bbase + (size_t)row * K + k0 + kc, &Bs[ch * 8]);
    }
    __syncthreads();
    sh8 af[4], bf[4];
#pragma unroll
    for (int i = 0; i < 4; ++i)
      af[i] = *(const sh8*)&As[(wr * 64 + i * 16 + r16) * 32 + ko];
#pragma unroll
    for (int j = 0; j < 4; ++j)
      bf[j] = *(const sh8*)&Bs[(wc * 64 + j * 16 + r16) * 32 + ko];
#pragma unroll
    for (int i = 0; i < 4; ++i)
#pragma unroll
      for (int j = 0; j < 4; ++j)
        acc[i][j] = __builtin_amdgcn_mfma_f32_16x16x32_bf16(af[i], bf[j],
                                                            acc[i][j], 0, 0, 0);
  }

  const int crow = wr * 64 + (lane >> 4) * 4;
  const int ccol = wc * 64 + r16;
#pragma unroll
  for (int i = 0; i < 4; ++i) {
#pragma unroll
    for (int j = 0; j < 4; ++j) {
      int col = bn * 128 + ccol + j * 16;
      float bv = bias ? bias[col] : 0.f;
#pragma unroll
      for (int r = 0; r < 4; ++r) {
        int row = bm * 128 + crow + i * 16 + r;
        float v = acc[i][j][r] + bv;
        if (OUT_BF16)
          ((short*)Cp)[(size_t)row * ldc + col] = f2bf(v);
        else
          ((float*)Cp)[(size_t)row * ldc + col] = v;
      }
    }
  }
}

// ---------------- bf16 GEMM, 256x128, 2 blocks/CU, depth-2 -----------------
// C[M,N] = A[M,K] @ Bt[N,K]^T + bias.  Grid: 1D, nwg = (M/256)*(N/128),
// nwg % 8 == 0 (XCD swizzle).  256 threads = 4 waves (2M x 2N), per-wave
// 128x64 output (8x4 16x16 frags).  LDS: 3 bufs x (A 16K + B 8K) = 72 KiB
// -> 2 blocks/CU.  BK=32, NT=K/32.  Depth-2: during tile t stage tile t+2
// into buf (t+2)%3 (that buf's reads finished at tile t-1's end barrier).
// Ledger: 6 loads/tile/wave; at tile end vmcnt(6) leaves t+2's 6, drains
// t+1's -> t+1 landed before its phase-0 reads.  Never vmcnt(0) in loop.
template <int OUT_BF16>
__global__ __launch_bounds__(256, 2) void gemmMain(
    const short* __restrict__ A, const short* __restrict__ Bt,
    void* __restrict__ Cp, const float* __restrict__ bias,
    int K, int ldc, int nbn) {
  __shared__ short lds[36864];  // 72 KiB: 3 bufs x 12288 shorts
  const int tid = threadIdx.x;
  const int lane = tid & 63, wid = tid >> 6;
  const int wr = wid >> 1, wc = wid & 1;
  const int r16 = lane & 15;
  const int kidx = ((lane >> 4) ^ ((r16 >> 1) & 3)) << 3;

  // XCD-aware swizzle (nwg % 8 == 0)
  const int cpx = gridDim.x >> 3;
  const int swz = (blockIdx.x & 7) * cpx + (blockIdx.x >> 3);
  const int bm = swz / nbn, bn = swz % nbn;

  const short* Ag = A + (size_t)bm * 256 * K;
  const short* Bg = Bt + (size_t)bn * 128 * K;

  // staging offsets: A = 1024 16B chunks (4/thread), B = 512 (2/thread)
  int gA[4], lA[4], gB[2], lB[2];
#pragma unroll
  for (int r = 0; r < 4; ++r) {
    int ch = r * 256 + tid, row = ch >> 2;
    int kc = (ch & 3) ^ ((row >> 1) & 3);
    gA[r] = row * K + kc * 8;
    lA[r] = ch * 8;
  }
#pragma unroll
  for (int r = 0; r < 2; ++r) {
    int ch = r * 256 + tid, row = ch >> 2;
    int kc = (ch & 3) ^ ((row >> 1) & 3);
    gB[r] = row * K + kc * 8;
    lB[r] = 8192 + ch * 8;
  }

  f4 acc[8][4] = {};
  const int NT = K >> 5;

#define STAGE6(KT, BUF)                                     \
  do {                                                      \
    short* lb = &lds[(BUF) * 12288];                        \
    const short* ga = Ag + (KT) * 32;                       \
    const short* gb = Bg + (KT) * 32;                       \
    g2l16(ga + gA[0], lb + lA[0]);                          \
    g2l16(ga + gA[1], lb + lA[1]);                          \
    g2l16(ga + gA[2], lb + lA[2]);                          \
    g2l16(ga + gA[3], lb + lA[3]);                          \
    g2l16(gb + gB[0], lb + lB[0]);                          \
    g2l16(gb + gB[1], lb + lB[1]);                          \
  } while (0)

  STAGE6(0, 0);
  STAGE6(1, 1);
  // tile 0 landed (newest 6 outstanding are tile 1's)
  asm volatile("s_waitcnt vmcnt(6)" ::: "memory");
  __builtin_amdgcn_sched_barrier(0);
  __builtin_amdgcn_s_barrier();

  for (int t = 0; t < NT; ++t) {
    const short* Ab = &lds[(t % 3) * 12288];
    const short* Bb = Ab + 8192;
    const int kt2 = (t + 2 < NT) ? t + 2 : 0;  // dummy reload: uniform ledger
    short* lb2 = &lds[((t + 2) % 3) * 12288];
    const short* ga2 = Ag + kt2 * 32;
    const short* gb2 = Bg + kt2 * 32;

    sh8 af[8], bfr[4];

    // -------- phase 0: A0-3 + B0-3 reads, stage half of t+2, 16 MFMA -------
#pragma unroll
    for (int i = 0; i < 4; ++i)
      af[i] = *(const sh8*)&Ab[(wr * 128 + i * 16 + r16) * 32 + kidx];
#pragma unroll
    for (int j = 0; j < 4; ++j)
      bfr[j] = *(const sh8*)&Bb[(wc * 64 + j * 16 + r16) * 32 + kidx];
    g2l16(ga2 + gA[0], lb2 + lA[0]);
    g2l16(ga2 + gA[1], lb2 + lA[1]);
    g2l16(gb2 + gB[0], lb2 + lB[0]);
    __builtin_amdgcn_sched_barrier(0);
    __builtin_amdgcn_s_barrier();
    asm volatile("s_waitcnt lgkmcnt(0)" ::: "memory");
    __builtin_amdgcn_sched_barrier(0);
    __builtin_amdgcn_s_setprio(1);
#pragma unroll
    for (int i = 0; i < 4; ++i)
#pragma unroll
      for (int j = 0; j < 4; ++j)
        acc[i][j] = __builtin_amdgcn_mfma_f32_16x16x32_bf16(af[i], bfr[j],
                                                            acc[i][j], 0, 0, 0);
    __builtin_amdgcn_s_setprio(0);
    __builtin_amdgcn_sched_barrier(0);
    __builtin_amdgcn_s_barrier();

    // -------- phase 1: A4-7 reads (B in regs), stage rest of t+2, 16 MFMA --
#pragma unroll
    for (int i = 4; i < 8; ++i)
      af[i] = *(const sh8*)&Ab[(wr * 128 + i * 16 + r16) * 32 + kidx];
    g2l16(ga2 + gA[2], lb2 + lA[2]);
    g2l16(ga2 + gA[3], lb2 + lA[3]);
    g2l16(gb2 + gB[1], lb2 + lB[1]);
    __builtin_amdgcn_sched_barrier(0);
    __builtin_amdgcn_s_barrier();
    asm volatile("s_waitcnt lgkmcnt(0)" ::: "memory");
    __builtin_amdgcn_sched_barrier(0);
    __builtin_amdgcn_s_setprio(1);
#pragma unroll
    for (int i = 4; i < 8; ++i)
#pragma unroll
      for (int j = 0; j < 4; ++j)
        acc[i][j] = __builtin_amdgcn_mfma_f32_16x16x32_bf16(af[i], bfr[j],
                                                            acc[i][j], 0, 0, 0);
    __builtin_amdgcn_s_setprio(0);
    __builtin_amdgcn_sched_barrier(0);
    // tile end: drain t+1's 6 loads (t+2's 6 remain outstanding)
    asm volatile("s_waitcnt vmcnt(6)" ::: "memory");
    __builtin_amdgcn_s_barrier();
  }
#undef STAGE6

  // C-write: j innermost -> 16-lane groups write contiguous 128B/256B rows.
  const int crow0 = bm * 256 + wr * 128 + (lane >> 4) * 4;
  const int ccol0 = bn * 128 + wc * 64 + r16;
  float bv[4];
#pragma unroll
  for (int j = 0; j < 4; ++j) bv[j] = bias ? bias[ccol0 + j * 16] : 0.f;
#pragma unroll
  for (int i = 0; i < 8; ++i) {
#pragma unroll
    for (int r = 0; r < 4; ++r) {
      size_t rowoff = (size_t)(crow0 + i * 16 + r) * ldc + ccol0;
#pragma unroll
      for (int j = 0; j < 4; ++j) {
        float v = acc[i][j][r] + bv[j];
        if (OUT_BF16)
          ((short*)Cp)[rowoff + j * 16] = f2bf(v);
        else
          ((float*)Cp)[rowoff + j * 16] = v;
      }
    }
  }
}

// --------------------------- per-token attention ---------------------------
__global__ __launch_bounds__(256) void attn_fused(
    const short* __restrict__ qkv, const float* __restrict__ pos_bias,
    short* __restrict__ xcat) {
  __shared__ short sq[4 * 3072];
  int t0 = blockIdx.x * 4;
  const sh8* gsrc = (const sh8*)(qkv + (size_t)t0 * 3072);
  sh8* ldst = (sh8*)sq;
#pragma unroll
  for (int c = 0; c < 6; ++c) ldst[threadIdx.x + c * 256] = gsrc[threadIdx.x + c * 256];
  __syncthreads();

  int wid = threadIdx.x >> 6, lane = threadIdx.x & 63;
  int t = t0 + wid, n = t & 4095;
  int h = lane >> 2, sub = lane & 3;
  const short* base = sq + wid * 3072 + h * 192;

  float qf[64];
#pragma unroll
  for (int c = 0; c < 8; ++c) {
    sh8 v8 = *(const sh8*)(base + c * 8);
#pragma unroll
    for (int j = 0; j < 8; ++j) qf[c * 8 + j] = bf2f(v8[j]);
  }

  const float* pb = pos_bias + (size_t)n * 256 + h * 16 + sub * 4;
  float p[4];
  float m = -1e30f;
#pragma unroll
  for (int g4 = 0; g4 < 4; ++g4) {
    int g = sub * 4 + g4;
    const short* kk = sq + wid * 3072 + g * 192 + 64;
    float acc = 0.f;
#pragma unroll
    for (int c = 0; c < 8; ++c) {
      sh8 k8 = *(const sh8*)(kk + c * 8);
#pragma unroll
      for (int j = 0; j < 8; ++j) acc += qf[c * 8 + j] * bf2f(k8[j]);
    }
    p[g4] = acc * 0.125f + pb[g4];
    m = fmaxf(m, p[g4]);
  }
  m = fmaxf(m, __shfl_xor(m, 1));
  m = fmaxf(m, __shfl_xor(m, 2));
  float sum = 0.f;
#pragma unroll
  for (int g4 = 0; g4 < 4; ++g4) {
    p[g4] = __expf(p[g4] - m);
    sum += p[g4];
  }
  sum += __shfl_xor(sum, 1);
  sum += __shfl_xor(sum, 2);
  float inv = 1.0f / sum;
#pragma unroll
  for (int g4 = 0; g4 < 4; ++g4) p[g4] *= inv;

  float pall[16];
#pragma unroll
  for (int g = 0; g < 16; ++g)
    pall[g] = __shfl(p[g & 3], (lane & 60) | (g >> 2));

  float o[16] = {};
#pragma unroll
  for (int g = 0; g < 16; ++g) {
    const short* vv = sq + wid * 3072 + g * 192 + 128 + sub * 16;
    sh8 va = *(const sh8*)vv;
    sh8 vb = *(const sh8*)(vv + 8);
#pragma unroll
    for (int j = 0; j < 8; ++j) {
      o[j] += pall[g] * bf2f(va[j]);
      o[8 + j] += pall[g] * bf2f(vb[j]);
    }
  }
  sh8 oa, ob;
#pragma unroll
  for (int j = 0; j < 8; ++j) {
    oa[j] = f2bf(o[j]);
    ob[j] = f2bf(o[8 + j]);
  }
  short* dst = xcat + (size_t)t * 2048 + h * 64 + sub * 16;
  *(sh8*)dst = oa;
  *(sh8*)(dst + 8) = ob;
}

// ------------------------- depthwise conv (k=3) ----------------------------
__global__ __launch_bounds__(256) void dwconv(
    const short* __restrict__ xc2, const float* __restrict__ dw0,
    const float* __restrict__ dw1, const float* __restrict__ dw2,
    const float* __restrict__ dwb, short* __restrict__ xcat) {
  int idx = blockIdx.x * 256 + threadIdx.x;  // 16384 * 128
  int t = idx >> 7, c = (idx & 127) * 8;
  int n = t & 4095;
  const short* row = xc2 + (size_t)t * 1024 + c;
  sh8 mid = *(const sh8*)row;
  sh8 lo = {}, hi = {};
  if (n > 0) lo = *(const sh8*)(row - 1024);
  if (n < 4095) hi = *(const sh8*)(row + 1024);
  sh8 out;
#pragma unroll
  for (int j = 0; j < 8; ++j) {
    float v = dw0[c + j] * bf2f(lo[j]) + dw1[c + j] * bf2f(mid[j]) +
              dw2[c + j] * bf2f(hi[j]) + dwb[c + j];
    out[j] = f2bf(v);
  }
  *(sh8*)(xcat + (size_t)t * 2048 + 1024 + c) = out;
}

// ---------------------------------------------------------------------------
extern "C" void kernel_launch(void* const* d_in, const int* in_sizes, int n_in,
                              void* d_out, int out_size, void* d_ws,
                              size_t ws_size, hipStream_t stream) {
  const float* x      = (const float*)d_in[0];
  const float* qkv_w  = (const float*)d_in[1];
  const float* qkv_b  = (const float*)d_in[2];
  const float* out_w  = (const float*)d_in[3];
  const float* out_b  = (const float*)d_in[4];
  const float* pos_b  = (const float*)d_in[5];
  const float* conv_w = (const float*)d_in[6];
  const float* conv_b = (const float*)d_in[7];
  const float* pw_w   = (const float*)d_in[8];
  const float* pw_b   = (const float*)d_in[9];
  const float* dw_w   = (const float*)d_in[10];
  const float* dw_b   = (const float*)d_in[11];
  const float* tok_w  = (const float*)d_in[12];
  const float* tok_b  = (const float*)d_in[13];

  const int M = 16384;
  char* ws = (char*)d_ws;
  size_t off = 0;
  auto alloc = [&](size_t bytes) -> void* {
    void* p = ws + off;
    off += (bytes + 255) & ~(size_t)255;
    return p;
  };
  short* xb    = (short*)alloc((size_t)M * 1024 * 2);
  short* qkvwt = (short*)alloc((size_t)3072 * 1024 * 2);
  short* wcatT = (short*)alloc((size_t)1024 * 2048 * 2);
  short* convb = (short*)alloc((size_t)1024 * 1024 * 2);
  short* pwb   = (short*)alloc((size_t)1024 * 1024 * 2);
  short* w2t   = (short*)alloc((size_t)1024 * 1024 * 2);
  short* qkvb  = (short*)alloc((size_t)M * 3072 * 2);
  short* xc2   = (short*)alloc((size_t)M * 1024 * 2);
  short* xcat  = (short*)alloc((size_t)M * 2048 * 2);
  float* b2    = (float*)alloc(1024 * 4);
  float* bcat  = (float*)alloc(1024 * 4);
  float* dw0   = (float*)alloc(1024 * 4);
  float* dw1   = (float*)alloc(1024 * 4);
  float* dw2   = (float*)alloc(1024 * 4);
  float* dwb   = (float*)alloc(1024 * 4);
  (void)ws_size; (void)in_sizes; (void)n_in; (void)out_size;

  // weight prep
  cvt_f32_bf16<<<8192, 256, 0, stream>>>(x, xb, M * 1024 / 8);
  cvt_f32_bf16<<<512, 256, 0, stream>>>(conv_w, convb, 1024 * 1024 / 8);
  cvt_f32_bf16<<<512, 256, 0, stream>>>(pw_w, pwb, 1024 * 1024 / 8);
  transpose_f32_bf16<<<dim3(96, 32), dim3(32, 8), 0, stream>>>(qkv_w, qkvwt, 3072, 1024, 0);
  transpose_f32_bf16<<<dim3(32, 32), dim3(32, 8), 0, stream>>>(out_w, wcatT, 1024, 2048, 0);
  transpose_f32_bf16<<<dim3(32, 32), dim3(32, 8), 0, stream>>>(tok_w, wcatT, 1024, 2048, 1024);
  prep_misc<<<1024, 256, 0, stream>>>(pw_w, conv_b, pw_b, out_b, tok_b, dw_w,
                                      dw_b, b2, bcat, dw0, dw1, dw2, dwb);
  // W2t[o][p] = sum_i pw_w[o][i] * conv_w[p][i]
  gemm128<1><<<dim3(8, 8), 256, 0, stream>>>(pwb, convb, w2t, nullptr, 1024, 1024);

  // main GEMMs (256x128 tile, 2 blocks/CU; grids %8==0 for XCD swizzle)
  gemmMain<1><<<1536, 256, 0, stream>>>(xb, qkvwt, qkvb, qkv_b, 1024, 3072, 24);
  gemmMain<1><<<512, 256, 0, stream>>>(xb, w2t, xc2, b2, 1024, 1024, 8);

  // branch epilogues into concatenated activation
  attn_fused<<<4096, 256, 0, stream>>>(qkvb, pos_b, xcat);
  dwconv<<<8192, 256, 0, stream>>>(xc2, dw0, dw1, dw2, dwb, xcat);

  // out = xcat @ [out_w; tok_w] + (out_b + tok_b)
  gemmMain<0><<<512, 256, 0, stream>>>(xcat, wcatT, d_out, bcat, 2048, 1024, 8);
}

// Round 8
// 338.354 us; speedup vs baseline: 1.0191x; 1.0191x over previous
//
#include <hip/hip_runtime.h>
#include <hip/hip_bf16.h>

// ---------------------------------------------------------------------------
// REMSA fused block on MI355X.
// Shapes: B=4, N=4096, C=1024, H=16, D=64. M = B*N = 16384.
//
// Decomposition:
//   xb    = bf16(x)                                   [M,1024]
//   W2    = conv_w @ pw_w^T (prefused), b2 fused      [1024,1024]
//   qkvx  = xb @ [qkv_w | W2] + [qkv_b | b2]          [M,4096]  (one GEMM256)
//   attn  = per-token 16x16 head-attn(qkvx[:, :3072]) [M,1024]  -> xcat[:, :1024]
//   xc3   = depthwise3(qkvx[:, 3072:]) + dw_b         [M,1024]  -> xcat[:, 1024:]
//   out   = xcat @ [out_w; tok_w] + (out_b+tok_b)     [M,1024]  (GEMM256 K=2048)
//
// gemm256: 256x256 tile, BK=32, 8 waves (2x4), 4 LDS buffers (128 KiB),
// depth-2 prefetch via global_load_lds, counted s_waitcnt vmcnt(4) (never 0),
// and exactly ONE s_barrier per K-tile (the only block-wide hazard is "all
// waves' tile-t+1 DMA landed"); waves may slide up to a full tile, so one
// wave's MFMA overlaps another's ds_read/stage window. Compiler handles
// ds_read->MFMA lgkmcnt (loads are compiler-visible). Bank swizzle:
// 16B chunk kc ^= (row>>1)&3 on global source + ds_read offsets (0 conflicts,
// verified rounds 4-6).
// ---------------------------------------------------------------------------

typedef __attribute__((ext_vector_type(8))) short sh8;
typedef __attribute__((ext_vector_type(4))) float f4;

__device__ __forceinline__ float bf2f(short s) {
  unsigned u = ((unsigned)(unsigned short)s) << 16;
  return __builtin_bit_cast(float, u);
}
__device__ __forceinline__ short f2bf(float f) {
  return __builtin_bit_cast(short, __float2bfloat16(f));
}
__device__ __forceinline__ void g2l16(const void* g, void* l) {
  __builtin_amdgcn_global_load_lds(
      (const __attribute__((address_space(1))) unsigned int*)g,
      (__attribute__((address_space(3))) unsigned int*)l, 16, 0, 0);
}

// --------------------------- f32 -> bf16 convert ---------------------------
__global__ __launch_bounds__(256) void cvt_f32_bf16(
    const float* __restrict__ src, short* __restrict__ dst, int n8) {
  int i = blockIdx.x * 256 + threadIdx.x;
  if (i >= n8) return;
  float4 a = ((const float4*)src)[i * 2];
  float4 b = ((const float4*)src)[i * 2 + 1];
  sh8 o;
  o[0] = f2bf(a.x); o[1] = f2bf(a.y); o[2] = f2bf(a.z); o[3] = f2bf(a.w);
  o[4] = f2bf(b.x); o[5] = f2bf(b.y); o[6] = f2bf(b.z); o[7] = f2bf(b.w);
  ((sh8*)dst)[i] = o;
}

// ------------------- transpose f32 (KxN) -> bf16 (N x ldd) -----------------
__global__ __launch_bounds__(256) void transpose_f32_bf16(
    const float* __restrict__ src, short* __restrict__ dst,
    int N, int ldd, int coff) {
  __shared__ float tile[32][33];
  int kb = blockIdx.y * 32, nb = blockIdx.x * 32;
  int tx = threadIdx.x, ty = threadIdx.y;
#pragma unroll
  for (int j = 0; j < 32; j += 8)
    tile[ty + j][tx] = src[(size_t)(kb + ty + j) * N + nb + tx];
  __syncthreads();
#pragma unroll
  for (int j = 0; j < 32; j += 8)
    dst[(size_t)(nb + ty + j) * ldd + coff + kb + tx] = f2bf(tile[tx][ty + j]);
}

// --------------------------- misc bias / dw prep ---------------------------
// grid = 3072 blocks. bias4 = [qkv_b | b2] (4096). For o<1024 also fills
// bcat (out_b+tok_b) and depthwise taps.
__global__ __launch_bounds__(256) void prep_misc(
    const float* __restrict__ pw_w, const float* __restrict__ conv_b,
    const float* __restrict__ pw_b, const float* __restrict__ qkv_b,
    const float* __restrict__ out_b, const float* __restrict__ tok_b,
    const float* __restrict__ dw_w, const float* __restrict__ dw_b,
    float* __restrict__ bias4, float* __restrict__ bcat,
    float* __restrict__ dw0, float* __restrict__ dw1,
    float* __restrict__ dw2, float* __restrict__ dwb) {
  int o = blockIdx.x;
  if (o < 1024) {
    float part = 0.f;
    for (int i = threadIdx.x; i < 1024; i += 256)
      part += pw_w[(size_t)o * 1024 + i] * conv_b[i];
#pragma unroll
    for (int off = 32; off >= 1; off >>= 1) part += __shfl_down(part, off);
    __shared__ float red[4];
    int wid = threadIdx.x >> 6, lane = threadIdx.x & 63;
    if (lane == 0) red[wid] = part;
    __syncthreads();
    if (threadIdx.x == 0) {
      float s = red[0] + red[1] + red[2] + red[3];
      bias4[3072 + o] = s + pw_b[o];
      bcat[o] = out_b[o] + tok_b[o];
      dw0[o] = dw_w[o * 3 + 0];
      dw1[o] = dw_w[o * 3 + 1];
      dw2[o] = dw_w[o * 3 + 2];
      dwb[o] = dw_b[o];
    }
  }
  if (threadIdx.x == 0) bias4[o] = qkv_b[o];
}

// --------------------- bf16 GEMM, 128x128 (prep only) ----------------------
template <int OUT_BF16>
__global__ __launch_bounds__(256, 2) void gemm128(
    const short* __restrict__ A, const short* __restrict__ Bt,
    void* __restrict__ Cp, const float* __restrict__ bias, int K, int ldc) {
  __shared__ short As[128 * 32];
  __shared__ short Bs[128 * 32];
  const int wid = threadIdx.x >> 6, lane = threadIdx.x & 63;
  const int bm = blockIdx.y, bn = blockIdx.x;
  const int wr = wid >> 1, wc = wid & 1;
  const size_t abase = (size_t)bm * 128 * K;
  const size_t bbase = (size_t)bn * 128 * K;
  const int r16 = lane & 15, ko = (lane >> 4) * 8;

  f4 acc[4][4] = {};

  for (int k0 = 0; k0 < K; k0 += 32) {
    __syncthreads();
#pragma unroll
    for (int c = 0; c < 2; ++c) {
      int ch = c * 256 + wid * 64 + lane;
      int row = ch >> 2, kc = (ch & 3) * 8;
      g2l16(A + abase + (size_t)row * K + k0 + kc, &As[ch * 8]);
      g2l16(Bt + bbase + (size_t)row * K + k0 + kc, &Bs[ch * 8]);
    }
    __syncthreads();
    sh8 af[4], bf[4];
#pragma unroll
    for (int i = 0; i < 4; ++i)
      af[i] = *(const sh8*)&As[(wr * 64 + i * 16 + r16) * 32 + ko];
#pragma unroll
    for (int j = 0; j < 4; ++j)
      bf[j] = *(const sh8*)&Bs[(wc * 64 + j * 16 + r16) * 32 + ko];
#pragma unroll
    for (int i = 0; i < 4; ++i)
#pragma unroll
      for (int j = 0; j < 4; ++j)
        acc[i][j] = __builtin_amdgcn_mfma_f32_16x16x32_bf16(af[i], bf[j],
                                                            acc[i][j], 0, 0, 0);
  }

  const int crow = wr * 64 + (lane >> 4) * 4;
  const int ccol = wc * 64 + r16;
#pragma unroll
  for (int i = 0; i < 4; ++i) {
#pragma unroll
    for (int j = 0; j < 4; ++j) {
      int col = bn * 128 + ccol + j * 16;
      float bv = bias ? bias[col] : 0.f;
#pragma unroll
      for (int r = 0; r < 4; ++r) {
        int row = bm * 128 + crow + i * 16 + r;
        float v = acc[i][j][r] + bv;
        if (OUT_BF16)
          ((short*)Cp)[(size_t)row * ldc + col] = f2bf(v);
        else
          ((float*)Cp)[(size_t)row * ldc + col] = v;
      }
    }
  }
}

// ---------- bf16 GEMM, 256x256, single-barrier-per-tile pipeline -----------
// C[M,N] = A[M,K] @ Bt[N,K]^T + bias.  Grid 1D, nwg % 8 == 0 (XCD swizzle).
// 512 threads = 8 waves (2M x 4N), per-wave 128x64 (8x4 16x16 frags).
// LDS: 4 bufs x 16384 shorts = 128 KiB.
// Depth-2: during tile t stage tile t+2 into buf (t+2)&3 (its readers all
// passed the end-of-t-1 barrier).  Per tile per thread: 4 g2l16.
// End of tile: per-wave vmcnt(4) (drains tile t+1's loads, leaves t+2's),
// then ONE s_barrier -> all waves' t+1 data landed.  No other barriers:
// waves slide within a tile, overlapping MFMA with reads/stages.
template <int OUT_BF16>
__global__ __launch_bounds__(512, 2) void gemm256(
    const short* __restrict__ A, const short* __restrict__ Bt,
    void* __restrict__ Cp, const float* __restrict__ bias,
    int K, int ldc, int nbn) {
  __shared__ short lds[65536];  // 128 KiB
  const int tid = threadIdx.x;
  const int lane = tid & 63, wid = tid >> 6;
  const int wr = wid >> 2, wc = wid & 3;
  const int r16 = lane & 15;
  const int kidx = ((lane >> 4) ^ ((r16 >> 1) & 3)) << 3;

  // XCD-aware swizzle (nwg % 8 == 0)
  const int cpx = gridDim.x >> 3;
  const int swz = (blockIdx.x & 7) * cpx + (blockIdx.x >> 3);
  const int bm = swz / nbn, bn = swz % nbn;

  const short* Ag = A + (size_t)bm * 256 * K;
  const short* Bg = Bt + (size_t)bn * 256 * K;

  int goff0, goff1, loff0, loff1;
  {
    int s0 = tid, row0 = s0 >> 2;
    int kc0 = (s0 & 3) ^ ((row0 >> 1) & 3);
    goff0 = row0 * K + kc0 * 8;
    loff0 = s0 * 8;
    int s1 = 512 + tid, row1 = s1 >> 2;
    int kc1 = (s1 & 3) ^ ((row1 >> 1) & 3);
    goff1 = row1 * K + kc1 * 8;
    loff1 = s1 * 8;
  }

  f4 acc[8][4] = {};
  const int NT = K >> 5;

#define STAGE_FULL(KT, B)                                   \
  do {                                                      \
    short* lb = &lds[(B) * 16384];                          \
    const short* ga = Ag + (KT) * 32;                       \
    const short* gb = Bg + (KT) * 32;                       \
    g2l16(ga + goff0, lb + loff0);                          \
    g2l16(gb + goff0, lb + 8192 + loff0);                   \
    g2l16(ga + goff1, lb + loff1);                          \
    g2l16(gb + goff1, lb + 8192 + loff1);                   \
  } while (0)

  STAGE_FULL(0, 0);
  STAGE_FULL(1, 1);
  asm volatile("s_waitcnt vmcnt(4)" ::: "memory");
  __builtin_amdgcn_sched_barrier(0);
  __builtin_amdgcn_s_barrier();
  __builtin_amdgcn_sched_barrier(0);

  for (int t = 0; t < NT; ++t) {
    const short* Ab = &lds[(t & 3) * 16384];
    const short* Bb = Ab + 8192;
    const int kt2 = (t + 2 < NT) ? t + 2 : 0;  // dummy reload: uniform ledger
    STAGE_FULL(kt2, (t + 2) & 3);              // issue-early (T14)

    sh8 af[8], bfr[4];
#pragma unroll
    for (int i = 0; i < 4; ++i)
      af[i] = *(const sh8*)&Ab[(wr * 128 + i * 16 + r16) * 32 + kidx];
#pragma unroll
    for (int j = 0; j < 4; ++j)
      bfr[j] = *(const sh8*)&Bb[(wc * 64 + j * 16 + r16) * 32 + kidx];
#pragma unroll
    for (int i = 4; i < 8; ++i)
      af[i] = *(const sh8*)&Ab[(wr * 128 + i * 16 + r16) * 32 + kidx];

    __builtin_amdgcn_s_setprio(1);
#pragma unroll
    for (int i = 0; i < 8; ++i)
#pragma unroll
      for (int j = 0; j < 4; ++j)
        acc[i][j] = __builtin_amdgcn_mfma_f32_16x16x32_bf16(af[i], bfr[j],
                                                            acc[i][j], 0, 0, 0);
    __builtin_amdgcn_s_setprio(0);
    __builtin_amdgcn_sched_barrier(0);
    // per-wave: tile t+1's 4 loads drained (t+2's 4 remain); then block-wide
    asm volatile("s_waitcnt vmcnt(4)" ::: "memory");
    __builtin_amdgcn_sched_barrier(0);
    __builtin_amdgcn_s_barrier();
    __builtin_amdgcn_sched_barrier(0);
  }
#undef STAGE_FULL

  // C-write: j innermost -> contiguous 128B (bf16) / 256B (f32) per row.
  const int crow0 = bm * 256 + wr * 128 + (lane >> 4) * 4;
  const int ccol0 = bn * 256 + wc * 64 + r16;
  float bv[4];
#pragma unroll
  for (int j = 0; j < 4; ++j) bv[j] = bias ? bias[ccol0 + j * 16] : 0.f;
#pragma unroll
  for (int i = 0; i < 8; ++i) {
#pragma unroll
    for (int r = 0; r < 4; ++r) {
      size_t rowoff = (size_t)(crow0 + i * 16 + r) * ldc + ccol0;
#pragma unroll
      for (int j = 0; j < 4; ++j) {
        float v = acc[i][j][r] + bv[j];
        if (OUT_BF16)
          ((short*)Cp)[rowoff + j * 16] = f2bf(v);
        else
          ((float*)Cp)[rowoff + j * 16] = v;
      }
    }
  }
}

// --------------------------- per-token attention ---------------------------
// reads qkvx rows (stride 4096), uses cols 0-3071 (head h at h*192).
__global__ __launch_bounds__(256) void attn_fused(
    const short* __restrict__ qkvx, const float* __restrict__ pos_bias,
    short* __restrict__ xcat) {
  __shared__ short sq[4 * 3072];
  int t0 = blockIdx.x * 4;
#pragma unroll
  for (int c = 0; c < 6; ++c) {
    int g = c * 256 + threadIdx.x;          // 1536 chunks = 4 tok x 384
    int tok = (g * 683) >> 18;              // g / 384 for g < 1536
    int off = g - tok * 384;
    ((sh8*)sq)[tok * 384 + off] =
        *(const sh8*)(qkvx + (size_t)(t0 + tok) * 4096 + off * 8);
  }
  __syncthreads();

  int wid = threadIdx.x >> 6, lane = threadIdx.x & 63;
  int t = t0 + wid, n = t & 4095;
  int h = lane >> 2, sub = lane & 3;
  const short* base = sq + wid * 3072 + h * 192;

  float qf[64];
#pragma unroll
  for (int c = 0; c < 8; ++c) {
    sh8 v8 = *(const sh8*)(base + c * 8);
#pragma unroll
    for (int j = 0; j < 8; ++j) qf[c * 8 + j] = bf2f(v8[j]);
  }

  const float* pb = pos_bias + (size_t)n * 256 + h * 16 + sub * 4;
  float p[4];
  float m = -1e30f;
#pragma unroll
  for (int g4 = 0; g4 < 4; ++g4) {
    int g = sub * 4 + g4;
    const short* kk = sq + wid * 3072 + g * 192 + 64;
    float acc = 0.f;
#pragma unroll
    for (int c = 0; c < 8; ++c) {
      sh8 k8 = *(const sh8*)(kk + c * 8);
#pragma unroll
      for (int j = 0; j < 8; ++j) acc += qf[c * 8 + j] * bf2f(k8[j]);
    }
    p[g4] = acc * 0.125f + pb[g4];
    m = fmaxf(m, p[g4]);
  }
  m = fmaxf(m, __shfl_xor(m, 1));
  m = fmaxf(m, __shfl_xor(m, 2));
  float sum = 0.f;
#pragma unroll
  for (int g4 = 0; g4 < 4; ++g4) {
    p[g4] = __expf(p[g4] - m);
    sum += p[g4];
  }
  sum += __shfl_xor(sum, 1);
  sum += __shfl_xor(sum, 2);
  float inv = 1.0f / sum;
#pragma unroll
  for (int g4 = 0; g4 < 4; ++g4) p[g4] *= inv;

  float pall[16];
#pragma unroll
  for (int g = 0; g < 16; ++g)
    pall[g] = __shfl(p[g & 3], (lane & 60) | (g >> 2));

  float o[16] = {};
#pragma unroll
  for (int g = 0; g < 16; ++g) {
    const short* vv = sq + wid * 3072 + g * 192 + 128 + sub * 16;
    sh8 va = *(const sh8*)vv;
    sh8 vb = *(const sh8*)(vv + 8);
#pragma unroll
    for (int j = 0; j < 8; ++j) {
      o[j] += pall[g] * bf2f(va[j]);
      o[8 + j] += pall[g] * bf2f(vb[j]);
    }
  }
  sh8 oa, ob;
#pragma unroll
  for (int j = 0; j < 8; ++j) {
    oa[j] = f2bf(o[j]);
    ob[j] = f2bf(o[8 + j]);
  }
  short* dst = xcat + (size_t)t * 2048 + h * 64 + sub * 16;
  *(sh8*)dst = oa;
  *(sh8*)(dst + 8) = ob;
}

// ------------------------- depthwise conv (k=3) ----------------------------
// reads qkvx cols 3072-4095 (stride 4096), writes xcat[:, 1024:].
__global__ __launch_bounds__(256) void dwconv(
    const short* __restrict__ qkvx, const float* __restrict__ dw0,
    const float* __restrict__ dw1, const float* __restrict__ dw2,
    const float* __restrict__ dwb, short* __restrict__ xcat) {
  int idx = blockIdx.x * 256 + threadIdx.x;  // 16384 * 128
  int t = idx >> 7, c = (idx & 127) * 8;
  int n = t & 4095;
  const short* row = qkvx + (size_t)t * 4096 + 3072 + c;
  sh8 mid = *(const sh8*)row;
  sh8 lo = {}, hi = {};
  if (n > 0) lo = *(const sh8*)(row - 4096);
  if (n < 4095) hi = *(const sh8*)(row + 4096);
  sh8 out;
#pragma unroll
  for (int j = 0; j < 8; ++j) {
    float v = dw0[c + j] * bf2f(lo[j]) + dw1[c + j] * bf2f(mid[j]) +
              dw2[c + j] * bf2f(hi[j]) + dwb[c + j];
    out[j] = f2bf(v);
  }
  *(sh8*)(xcat + (size_t)t * 2048 + 1024 + c) = out;
}

// ---------------------------------------------------------------------------
extern "C" void kernel_launch(void* const* d_in, const int* in_sizes, int n_in,
                              void* d_out, int out_size, void* d_ws,
                              size_t ws_size, hipStream_t stream) {
  const float* x      = (const float*)d_in[0];
  const float* qkv_w  = (const float*)d_in[1];
  const float* qkv_b  = (const float*)d_in[2];
  const float* out_w  = (const float*)d_in[3];
  const float* out_b  = (const float*)d_in[4];
  const float* pos_b  = (const float*)d_in[5];
  const float* conv_w = (const float*)d_in[6];
  const float* conv_b = (const float*)d_in[7];
  const float* pw_w   = (const float*)d_in[8];
  const float* pw_b   = (const float*)d_in[9];
  const float* dw_w   = (const float*)d_in[10];
  const float* dw_b   = (const float*)d_in[11];
  const float* tok_w  = (const float*)d_in[12];
  const float* tok_b  = (const float*)d_in[13];

  const int M = 16384;
  char* ws = (char*)d_ws;
  size_t off = 0;
  auto alloc = [&](size_t bytes) -> void* {
    void* p = ws + off;
    off += (bytes + 255) & ~(size_t)255;
    return p;
  };
  short* xb    = (short*)alloc((size_t)M * 1024 * 2);
  short* wbig  = (short*)alloc((size_t)4096 * 1024 * 2);  // [qkv_w^T | W2^T]
  short* wcatT = (short*)alloc((size_t)1024 * 2048 * 2);
  short* convb = (short*)alloc((size_t)1024 * 1024 * 2);
  short* pwb   = (short*)alloc((size_t)1024 * 1024 * 2);
  short* qkvx  = (short*)alloc((size_t)M * 4096 * 2);
  short* xcat  = (short*)alloc((size_t)M * 2048 * 2);
  float* bias4 = (float*)alloc(4096 * 4);
  float* bcat  = (float*)alloc(1024 * 4);
  float* dw0   = (float*)alloc(1024 * 4);
  float* dw1   = (float*)alloc(1024 * 4);
  float* dw2   = (float*)alloc(1024 * 4);
  float* dwb   = (float*)alloc(1024 * 4);
  (void)ws_size; (void)in_sizes; (void)n_in; (void)out_size;

  // weight prep
  cvt_f32_bf16<<<8192, 256, 0, stream>>>(x, xb, M * 1024 / 8);
  cvt_f32_bf16<<<512, 256, 0, stream>>>(conv_w, convb, 1024 * 1024 / 8);
  cvt_f32_bf16<<<512, 256, 0, stream>>>(pw_w, pwb, 1024 * 1024 / 8);
  transpose_f32_bf16<<<dim3(96, 32), dim3(32, 8), 0, stream>>>(qkv_w, wbig, 3072, 1024, 0);
  transpose_f32_bf16<<<dim3(32, 32), dim3(32, 8), 0, stream>>>(out_w, wcatT, 1024, 2048, 0);
  transpose_f32_bf16<<<dim3(32, 32), dim3(32, 8), 0, stream>>>(tok_w, wcatT, 1024, 2048, 1024);
  prep_misc<<<3072, 256, 0, stream>>>(pw_w, conv_b, pw_b, qkv_b, out_b, tok_b,
                                      dw_w, dw_b, bias4, bcat, dw0, dw1, dw2, dwb);
  // W2^T[o][p] = sum_i pw_w[o][i] * conv_w[p][i] -> rows 3072+ of wbig
  gemm128<1><<<dim3(8, 8), 256, 0, stream>>>(pwb, convb, wbig + (size_t)3072 * 1024,
                                             nullptr, 1024, 1024);

  // fused qkv+conv GEMM: [M,1024] @ [4096,1024]^T -> [M,4096]
  gemm256<1><<<1024, 512, 0, stream>>>(xb, wbig, qkvx, bias4, 1024, 4096, 16);

  // branch epilogues into concatenated activation
  attn_fused<<<4096, 256, 0, stream>>>(qkvx, pos_b, xcat);
  dwconv<<<8192, 256, 0, stream>>>(qkvx, dw0, dw1, dw2, dwb, xcat);

  // out = xcat @ [out_w; tok_w] + (out_b + tok_b)
  gemm256<0><<<256, 512, 0, stream>>>(xcat, wcatT, d_out, bcat, 2048, 1024, 4);
}

// Round 9
// 330.355 us; speedup vs baseline: 1.0438x; 1.0242x over previous
//
#include <hip/hip_runtime.h>
#include <hip/hip_bf16.h>

// ---------------------------------------------------------------------------
// REMSA fused block on MI355X.
// Shapes: B=4, N=4096, C=1024, H=16, D=64. M = B*N = 16384.
//
// Decomposition:
//   xb    = bf16(x)                                   [M,1024]
//   W2    = conv_w @ pw_w^T (prefused), b2 fused      [1024,1024]
//   qkvx  = xb @ [qkv_w | W2] + [qkv_b | b2]          [M,4096]  (one GEMM256)
//   attn  = per-token 16x16 head-attn(qkvx[:, :3072]) [M,1024]  -> xcat[:, :1024]
//   xc3   = depthwise3(qkvx[:, 3072:]) + dw_b         [M,1024]  -> xcat[:, 1024:]
//   out   = xcat @ [out_w; tok_w] + (out_b+tok_b)     [M,1024]  (GEMM256 K=2048)
//
// gemm256 v3: 256x256 tile, BK=32, 8 waves (2x4), 4 LDS bufs (128 KiB),
// REGISTER-double-buffered fragments: tile t+1's 12 ds_read_b128 are issued
// into a second named register set during tile t's 32-MFMA cluster (no lgkm
// dependency -> LDS pipe drains under the matrix pipe). DMA depth-3 via
// global_load_lds: stage t+3 during t; end-of-tile vmcnt(4) (never 0) drains
// t+2's loads; ONE s_barrier per tile. Unroll-by-2 with named sets afA/afB
// (rule #20: no runtime-indexed reg arrays). Bank swizzle: 16B chunk
// kc ^= (row>>1)&3 on global source + ds_read offsets (0 conflicts,
// verified rounds 4-8).
// ---------------------------------------------------------------------------

typedef __attribute__((ext_vector_type(8))) short sh8;
typedef __attribute__((ext_vector_type(4))) float f4;

__device__ __forceinline__ float bf2f(short s) {
  unsigned u = ((unsigned)(unsigned short)s) << 16;
  return __builtin_bit_cast(float, u);
}
__device__ __forceinline__ short f2bf(float f) {
  return __builtin_bit_cast(short, __float2bfloat16(f));
}
__device__ __forceinline__ void g2l16(const void* g, void* l) {
  __builtin_amdgcn_global_load_lds(
      (const __attribute__((address_space(1))) unsigned int*)g,
      (__attribute__((address_space(3))) unsigned int*)l, 16, 0, 0);
}

// --------------------------- f32 -> bf16 convert ---------------------------
__global__ __launch_bounds__(256) void cvt_f32_bf16(
    const float* __restrict__ src, short* __restrict__ dst, int n8) {
  int i = blockIdx.x * 256 + threadIdx.x;
  if (i >= n8) return;
  float4 a = ((const float4*)src)[i * 2];
  float4 b = ((const float4*)src)[i * 2 + 1];
  sh8 o;
  o[0] = f2bf(a.x); o[1] = f2bf(a.y); o[2] = f2bf(a.z); o[3] = f2bf(a.w);
  o[4] = f2bf(b.x); o[5] = f2bf(b.y); o[6] = f2bf(b.z); o[7] = f2bf(b.w);
  ((sh8*)dst)[i] = o;
}

// ------------------- transpose f32 (KxN) -> bf16 (N x ldd) -----------------
__global__ __launch_bounds__(256) void transpose_f32_bf16(
    const float* __restrict__ src, short* __restrict__ dst,
    int N, int ldd, int coff) {
  __shared__ float tile[32][33];
  int kb = blockIdx.y * 32, nb = blockIdx.x * 32;
  int tx = threadIdx.x, ty = threadIdx.y;
#pragma unroll
  for (int j = 0; j < 32; j += 8)
    tile[ty + j][tx] = src[(size_t)(kb + ty + j) * N + nb + tx];
  __syncthreads();
#pragma unroll
  for (int j = 0; j < 32; j += 8)
    dst[(size_t)(nb + ty + j) * ldd + coff + kb + tx] = f2bf(tile[tx][ty + j]);
}

// --------------------------- misc bias / dw prep ---------------------------
// grid = 3072 blocks. bias4 = [qkv_b | b2] (4096). For o<1024 also fills
// bcat (out_b+tok_b) and depthwise taps.
__global__ __launch_bounds__(256) void prep_misc(
    const float* __restrict__ pw_w, const float* __restrict__ conv_b,
    const float* __restrict__ pw_b, const float* __restrict__ qkv_b,
    const float* __restrict__ out_b, const float* __restrict__ tok_b,
    const float* __restrict__ dw_w, const float* __restrict__ dw_b,
    float* __restrict__ bias4, float* __restrict__ bcat,
    float* __restrict__ dw0, float* __restrict__ dw1,
    float* __restrict__ dw2, float* __restrict__ dwb) {
  int o = blockIdx.x;
  if (o < 1024) {
    float part = 0.f;
    for (int i = threadIdx.x; i < 1024; i += 256)
      part += pw_w[(size_t)o * 1024 + i] * conv_b[i];
#pragma unroll
    for (int off = 32; off >= 1; off >>= 1) part += __shfl_down(part, off);
    __shared__ float red[4];
    int wid = threadIdx.x >> 6, lane = threadIdx.x & 63;
    if (lane == 0) red[wid] = part;
    __syncthreads();
    if (threadIdx.x == 0) {
      float s = red[0] + red[1] + red[2] + red[3];
      bias4[3072 + o] = s + pw_b[o];
      bcat[o] = out_b[o] + tok_b[o];
      dw0[o] = dw_w[o * 3 + 0];
      dw1[o] = dw_w[o * 3 + 1];
      dw2[o] = dw_w[o * 3 + 2];
      dwb[o] = dw_b[o];
    }
  }
  if (threadIdx.x == 0) bias4[o] = qkv_b[o];
}

// --------------------- bf16 GEMM, 128x128 (prep only) ----------------------
template <int OUT_BF16>
__global__ __launch_bounds__(256, 2) void gemm128(
    const short* __restrict__ A, const short* __restrict__ Bt,
    void* __restrict__ Cp, const float* __restrict__ bias, int K, int ldc) {
  __shared__ short As[128 * 32];
  __shared__ short Bs[128 * 32];
  const int wid = threadIdx.x >> 6, lane = threadIdx.x & 63;
  const int bm = blockIdx.y, bn = blockIdx.x;
  const int wr = wid >> 1, wc = wid & 1;
  const size_t abase = (size_t)bm * 128 * K;
  const size_t bbase = (size_t)bn * 128 * K;
  const int r16 = lane & 15, ko = (lane >> 4) * 8;

  f4 acc[4][4] = {};

  for (int k0 = 0; k0 < K; k0 += 32) {
    __syncthreads();
#pragma unroll
    for (int c = 0; c < 2; ++c) {
      int ch = c * 256 + wid * 64 + lane;
      int row = ch >> 2, kc = (ch & 3) * 8;
      g2l16(A + abase + (size_t)row * K + k0 + kc, &As[ch * 8]);
      g2l16(Bt + bbase + (size_t)row * K + k0 + kc, &Bs[ch * 8]);
    }
    __syncthreads();
    sh8 af[4], bf[4];
#pragma unroll
    for (int i = 0; i < 4; ++i)
      af[i] = *(const sh8*)&As[(wr * 64 + i * 16 + r16) * 32 + ko];
#pragma unroll
    for (int j = 0; j < 4; ++j)
      bf[j] = *(const sh8*)&Bs[(wc * 64 + j * 16 + r16) * 32 + ko];
#pragma unroll
    for (int i = 0; i < 4; ++i)
#pragma unroll
      for (int j = 0; j < 4; ++j)
        acc[i][j] = __builtin_amdgcn_mfma_f32_16x16x32_bf16(af[i], bf[j],
                                                            acc[i][j], 0, 0, 0);
  }

  const int crow = wr * 64 + (lane >> 4) * 4;
  const int ccol = wc * 64 + r16;
#pragma unroll
  for (int i = 0; i < 4; ++i) {
#pragma unroll
    for (int j = 0; j < 4; ++j) {
      int col = bn * 128 + ccol + j * 16;
      float bv = bias ? bias[col] : 0.f;
#pragma unroll
      for (int r = 0; r < 4; ++r) {
        int row = bm * 128 + crow + i * 16 + r;
        float v = acc[i][j][r] + bv;
        if (OUT_BF16)
          ((short*)Cp)[(size_t)row * ldc + col] = f2bf(v);
        else
          ((float*)Cp)[(size_t)row * ldc + col] = v;
      }
    }
  }
}

// ------- bf16 GEMM, 256x256, register-dbuf fragments + depth-3 DMA ---------
// C[M,N] = A[M,K] @ Bt[N,K]^T + bias.  Grid 1D, nwg % 8 == 0 (XCD swizzle).
// 512 threads = 8 waves (2M x 4N), per-wave 128x64 (8x4 16x16 frags).
// LDS: 4 bufs x 16384 shorts = 128 KiB -> 1 block/CU.
// Steady state per tile t: {issue 12 ds_read for tile t+1 into spare reg set;
// issue 4 DMA for tile t+3; 32 MFMA on current reg set (overlaps the reads);
// vmcnt(4); s_barrier}.  NT must be even, >= 4.
template <int OUT_BF16>
__global__ __launch_bounds__(512, 2) void gemm256(
    const short* __restrict__ A, const short* __restrict__ Bt,
    void* __restrict__ Cp, const float* __restrict__ bias,
    int K, int ldc, int nbn) {
  __shared__ short lds[65536];  // 128 KiB
  const int tid = threadIdx.x;
  const int lane = tid & 63, wid = tid >> 6;
  const int wr = wid >> 2, wc = wid & 3;
  const int r16 = lane & 15;
  const int kidx = ((lane >> 4) ^ ((r16 >> 1) & 3)) << 3;

  // XCD-aware swizzle (nwg % 8 == 0)
  const int cpx = gridDim.x >> 3;
  const int swz = (blockIdx.x & 7) * cpx + (blockIdx.x >> 3);
  const int bm = swz / nbn, bn = swz % nbn;

  const short* Ag = A + (size_t)bm * 256 * K;
  const short* Bg = Bt + (size_t)bn * 256 * K;

  int goff0, goff1, loff0, loff1;
  {
    int s0 = tid, row0 = s0 >> 2;
    int kc0 = (s0 & 3) ^ ((row0 >> 1) & 3);
    goff0 = row0 * K + kc0 * 8;
    loff0 = s0 * 8;
    int s1 = 512 + tid, row1 = s1 >> 2;
    int kc1 = (s1 & 3) ^ ((row1 >> 1) & 3);
    goff1 = row1 * K + kc1 * 8;
    loff1 = s1 * 8;
  }

  f4 acc[8][4] = {};
  const int NT = K >> 5;

#define STAGE_FULL(KT, B)                                   \
  do {                                                      \
    short* lb = &lds[(B) * 16384];                          \
    const short* ga = Ag + (KT) * 32;                       \
    const short* gb = Bg + (KT) * 32;                       \
    g2l16(ga + goff0, lb + loff0);                          \
    g2l16(gb + goff0, lb + 8192 + loff0);                   \
    g2l16(ga + goff1, lb + loff1);                          \
    g2l16(gb + goff1, lb + 8192 + loff1);                   \
  } while (0)

#define LOADFRAG(AF, BF, BUFIDX)                                          \
  do {                                                                    \
    const short* Ab_ = &lds[(BUFIDX) * 16384];                            \
    const short* Bb_ = Ab_ + 8192;                                        \
    _Pragma("unroll")                                                     \
    for (int i = 0; i < 8; ++i)                                           \
      AF[i] = *(const sh8*)&Ab_[(wr * 128 + i * 16 + r16) * 32 + kidx];   \
    _Pragma("unroll")                                                     \
    for (int j = 0; j < 4; ++j)                                           \
      BF[j] = *(const sh8*)&Bb_[(wc * 64 + j * 16 + r16) * 32 + kidx];    \
  } while (0)

#define MFMA_ALL(AF, BF)                                                  \
  do {                                                                    \
    _Pragma("unroll")                                                     \
    for (int i = 0; i < 8; ++i)                                           \
      _Pragma("unroll")                                                   \
      for (int j = 0; j < 4; ++j)                                         \
        acc[i][j] = __builtin_amdgcn_mfma_f32_16x16x32_bf16(              \
            AF[i], BF[j], acc[i][j], 0, 0, 0);                            \
  } while (0)

  // prologue: stage tiles 0,1,2; ensure 0,1 landed block-wide.
  STAGE_FULL(0, 0);
  STAGE_FULL(1, 1);
  STAGE_FULL(2, 2);
  asm volatile("s_waitcnt vmcnt(4)" ::: "memory");
  __builtin_amdgcn_sched_barrier(0);
  __builtin_amdgcn_s_barrier();
  __builtin_amdgcn_sched_barrier(0);

  sh8 afA[8], bfA[4], afB[8], bfB[4];
  LOADFRAG(afA, bfA, 0);  // fragments for tile 0

  for (int t = 0; t < NT; t += 2) {
    // ---- even tile t: compute with A-set, prefetch t+1 into B-set --------
    LOADFRAG(afB, bfB, (t + 1) & 3);
    {
      const int kt = (t + 3 < NT) ? t + 3 : 0;  // dummy reload: uniform ledger
      STAGE_FULL(kt, (t + 3) & 3);
    }
    __builtin_amdgcn_s_setprio(1);
    MFMA_ALL(afA, bfA);
    __builtin_amdgcn_s_setprio(0);
    __builtin_amdgcn_sched_barrier(0);
    asm volatile("s_waitcnt vmcnt(4)" ::: "memory");  // t+2 landed
    __builtin_amdgcn_sched_barrier(0);
    __builtin_amdgcn_s_barrier();
    __builtin_amdgcn_sched_barrier(0);

    // ---- odd tile t+1: compute with B-set, prefetch t+2 into A-set -------
    LOADFRAG(afA, bfA, (t + 2) & 3);
    {
      const int kt = (t + 4 < NT) ? t + 4 : 0;
      STAGE_FULL(kt, (t + 4) & 3);
    }
    __builtin_amdgcn_s_setprio(1);
    MFMA_ALL(afB, bfB);
    __builtin_amdgcn_s_setprio(0);
    __builtin_amdgcn_sched_barrier(0);
    asm volatile("s_waitcnt vmcnt(4)" ::: "memory");  // t+3 landed
    __builtin_amdgcn_sched_barrier(0);
    __builtin_amdgcn_s_barrier();
    __builtin_amdgcn_sched_barrier(0);
  }
#undef STAGE_FULL
#undef LOADFRAG
#undef MFMA_ALL

  // C-write: j innermost -> contiguous 128B (bf16) / 256B (f32) per row.
  const int crow0 = bm * 256 + wr * 128 + (lane >> 4) * 4;
  const int ccol0 = bn * 256 + wc * 64 + r16;
  float bv[4];
#pragma unroll
  for (int j = 0; j < 4; ++j) bv[j] = bias ? bias[ccol0 + j * 16] : 0.f;
#pragma unroll
  for (int i = 0; i < 8; ++i) {
#pragma unroll
    for (int r = 0; r < 4; ++r) {
      size_t rowoff = (size_t)(crow0 + i * 16 + r) * ldc + ccol0;
#pragma unroll
      for (int j = 0; j < 4; ++j) {
        float v = acc[i][j][r] + bv[j];
        if (OUT_BF16)
          ((short*)Cp)[rowoff + j * 16] = f2bf(v);
        else
          ((float*)Cp)[rowoff + j * 16] = v;
      }
    }
  }
}

// --------------------------- per-token attention ---------------------------
// reads qkvx rows (stride 4096), uses cols 0-3071 (head h at h*192).
__global__ __launch_bounds__(256) void attn_fused(
    const short* __restrict__ qkvx, const float* __restrict__ pos_bias,
    short* __restrict__ xcat) {
  __shared__ short sq[4 * 3072];
  int t0 = blockIdx.x * 4;
#pragma unroll
  for (int c = 0; c < 6; ++c) {
    int g = c * 256 + threadIdx.x;          // 1536 chunks = 4 tok x 384
    int tok = (g * 683) >> 18;              // g / 384 for g < 1536
    int off = g - tok * 384;
    ((sh8*)sq)[tok * 384 + off] =
        *(const sh8*)(qkvx + (size_t)(t0 + tok) * 4096 + off * 8);
  }
  __syncthreads();

  int wid = threadIdx.x >> 6, lane = threadIdx.x & 63;
  int t = t0 + wid, n = t & 4095;
  int h = lane >> 2, sub = lane & 3;
  const short* base = sq + wid * 3072 + h * 192;

  float qf[64];
#pragma unroll
  for (int c = 0; c < 8; ++c) {
    sh8 v8 = *(const sh8*)(base + c * 8);
#pragma unroll
    for (int j = 0; j < 8; ++j) qf[c * 8 + j] = bf2f(v8[j]);
  }

  const float* pb = pos_bias + (size_t)n * 256 + h * 16 + sub * 4;
  float p[4];
  float m = -1e30f;
#pragma unroll
  for (int g4 = 0; g4 < 4; ++g4) {
    int g = sub * 4 + g4;
    const short* kk = sq + wid * 3072 + g * 192 + 64;
    float acc = 0.f;
#pragma unroll
    for (int c = 0; c < 8; ++c) {
      sh8 k8 = *(const sh8*)(kk + c * 8);
#pragma unroll
      for (int j = 0; j < 8; ++j) acc += qf[c * 8 + j] * bf2f(k8[j]);
    }
    p[g4] = acc * 0.125f + pb[g4];
    m = fmaxf(m, p[g4]);
  }
  m = fmaxf(m, __shfl_xor(m, 1));
  m = fmaxf(m, __shfl_xor(m, 2));
  float sum = 0.f;
#pragma unroll
  for (int g4 = 0; g4 < 4; ++g4) {
    p[g4] = __expf(p[g4] - m);
    sum += p[g4];
  }
  sum += __shfl_xor(sum, 1);
  sum += __shfl_xor(sum, 2);
  float inv = 1.0f / sum;
#pragma unroll
  for (int g4 = 0; g4 < 4; ++g4) p[g4] *= inv;

  float pall[16];
#pragma unroll
  for (int g = 0; g < 16; ++g)
    pall[g] = __shfl(p[g & 3], (lane & 60) | (g >> 2));

  float o[16] = {};
#pragma unroll
  for (int g = 0; g < 16; ++g) {
    const short* vv = sq + wid * 3072 + g * 192 + 128 + sub * 16;
    sh8 va = *(const sh8*)vv;
    sh8 vb = *(const sh8*)(vv + 8);
#pragma unroll
    for (int j = 0; j < 8; ++j) {
      o[j] += pall[g] * bf2f(va[j]);
      o[8 + j] += pall[g] * bf2f(vb[j]);
    }
  }
  sh8 oa, ob;
#pragma unroll
  for (int j = 0; j < 8; ++j) {
    oa[j] = f2bf(o[j]);
    ob[j] = f2bf(o[8 + j]);
  }
  short* dst = xcat + (size_t)t * 2048 + h * 64 + sub * 16;
  *(sh8*)dst = oa;
  *(sh8*)(dst + 8) = ob;
}

// ------------------------- depthwise conv (k=3) ----------------------------
// reads qkvx cols 3072-4095 (stride 4096), writes xcat[:, 1024:].
__global__ __launch_bounds__(256) void dwconv(
    const short* __restrict__ qkvx, const float* __restrict__ dw0,
    const float* __restrict__ dw1, const float* __restrict__ dw2,
    const float* __restrict__ dwb, short* __restrict__ xcat) {
  int idx = blockIdx.x * 256 + threadIdx.x;  // 16384 * 128
  int t = idx >> 7, c = (idx & 127) * 8;
  int n = t & 4095;
  const short* row = qkvx + (size_t)t * 4096 + 3072 + c;
  sh8 mid = *(const sh8*)row;
  sh8 lo = {}, hi = {};
  if (n > 0) lo = *(const sh8*)(row - 4096);
  if (n < 4095) hi = *(const sh8*)(row + 4096);
  sh8 out;
#pragma unroll
  for (int j = 0; j < 8; ++j) {
    float v = dw0[c + j] * bf2f(lo[j]) + dw1[c + j] * bf2f(mid[j]) +
              dw2[c + j] * bf2f(hi[j]) + dwb[c + j];
    out[j] = f2bf(v);
  }
  *(sh8*)(xcat + (size_t)t * 2048 + 1024 + c) = out;
}

// ---------------------------------------------------------------------------
extern "C" void kernel_launch(void* const* d_in, const int* in_sizes, int n_in,
                              void* d_out, int out_size, void* d_ws,
                              size_t ws_size, hipStream_t stream) {
  const float* x      = (const float*)d_in[0];
  const float* qkv_w  = (const float*)d_in[1];
  const float* qkv_b  = (const float*)d_in[2];
  const float* out_w  = (const float*)d_in[3];
  const float* out_b  = (const float*)d_in[4];
  const float* pos_b  = (const float*)d_in[5];
  const float* conv_w = (const float*)d_in[6];
  const float* conv_b = (const float*)d_in[7];
  const float* pw_w   = (const float*)d_in[8];
  const float* pw_b   = (const float*)d_in[9];
  const float* dw_w   = (const float*)d_in[10];
  const float* dw_b   = (const float*)d_in[11];
  const float* tok_w  = (const float*)d_in[12];
  const float* tok_b  = (const float*)d_in[13];

  const int M = 16384;
  char* ws = (char*)d_ws;
  size_t off = 0;
  auto alloc = [&](size_t bytes) -> void* {
    void* p = ws + off;
    off += (bytes + 255) & ~(size_t)255;
    return p;
  };
  short* xb    = (short*)alloc((size_t)M * 1024 * 2);
  short* wbig  = (short*)alloc((size_t)4096 * 1024 * 2);  // [qkv_w^T | W2^T]
  short* wcatT = (short*)alloc((size_t)1024 * 2048 * 2);
  short* convb = (short*)alloc((size_t)1024 * 1024 * 2);
  short* pwb   = (short*)alloc((size_t)1024 * 1024 * 2);
  short* qkvx  = (short*)alloc((size_t)M * 4096 * 2);
  short* xcat  = (short*)alloc((size_t)M * 2048 * 2);
  float* bias4 = (float*)alloc(4096 * 4);
  float* bcat  = (float*)alloc(1024 * 4);
  float* dw0   = (float*)alloc(1024 * 4);
  float* dw1   = (float*)alloc(1024 * 4);
  float* dw2   = (float*)alloc(1024 * 4);
  float* dwb   = (float*)alloc(1024 * 4);
  (void)ws_size; (void)in_sizes; (void)n_in; (void)out_size;

  // weight prep
  cvt_f32_bf16<<<8192, 256, 0, stream>>>(x, xb, M * 1024 / 8);
  cvt_f32_bf16<<<512, 256, 0, stream>>>(conv_w, convb, 1024 * 1024 / 8);
  cvt_f32_bf16<<<512, 256, 0, stream>>>(pw_w, pwb, 1024 * 1024 / 8);
  transpose_f32_bf16<<<dim3(96, 32), dim3(32, 8), 0, stream>>>(qkv_w, wbig, 3072, 1024, 0);
  transpose_f32_bf16<<<dim3(32, 32), dim3(32, 8), 0, stream>>>(out_w, wcatT, 1024, 2048, 0);
  transpose_f32_bf16<<<dim3(32, 32), dim3(32, 8), 0, stream>>>(tok_w, wcatT, 1024, 2048, 1024);
  prep_misc<<<3072, 256, 0, stream>>>(pw_w, conv_b, pw_b, qkv_b, out_b, tok_b,
                                      dw_w, dw_b, bias4, bcat, dw0, dw1, dw2, dwb);
  // W2^T[o][p] = sum_i pw_w[o][i] * conv_w[p][i] -> rows 3072+ of wbig
  gemm128<1><<<dim3(8, 8), 256, 0, stream>>>(pwb, convb, wbig + (size_t)3072 * 1024,
                                             nullptr, 1024, 1024);

  // fused qkv+conv GEMM: [M,1024] @ [4096,1024]^T -> [M,4096]
  gemm256<1><<<1024, 512, 0, stream>>>(xb, wbig, qkvx, bias4, 1024, 4096, 16);

  // branch epilogues into concatenated activation
  attn_fused<<<4096, 256, 0, stream>>>(qkvx, pos_b, xcat);
  dwconv<<<8192, 256, 0, stream>>>(qkvx, dw0, dw1, dw2, dwb, xcat);

  // out = xcat @ [out_w; tok_w] + (out_b + tok_b)
  gemm256<0><<<256, 512, 0, stream>>>(xcat, wcatT, d_out, bcat, 2048, 1024, 4);
}